// Round 3
// baseline (724.193 us; speedup 1.0000x reference)
//
#include <hip/hip_runtime.h>

// ---------------------------------------------------------------------------
// SpatialAttention3D: B=2, C=384, D=H=W=32, HEADS=12, HD=32, WS=5, PAD=2
// I/O dtype: float32. Intermediates q/k/v/a: bf16.
// R8:
//   - qkv/proj: grid dims swapped (o-tile fastest) so consecutive blocks share
//     the same x/a s-tile through L2/L3 -> x no longer fetched 9x (3x for a).
//   - attn3d VALU-count cuts (was VALU-issue-bound at 67% busy):
//       * v_cvt_pk_bf16_f32 packing (P, QPE, output) via inline asm
//       * sentinel-free masked gather: noff byte-offset regs + maskf zeroing
//         after exp2 (running max may include out-of-window scores: softmax
//         o/l ratio is invariant to a uniformly larger max)
//       * T14 async staging: chunk c+1 K/V global->reg loads issued before
//         compute of chunk c (HBM latency hidden under ~2 softmax layers)
// ---------------------------------------------------------------------------

#define NB 2
#define NC 384
#define NHEADS 12
#define NHD 32
#define NS 32768               // 32*32*32
#define PERB 12582912          // NC*NS (one batch of out / qkv third)
#define SCALE_F 0.17677669529663687f
#define LOG2E_F 1.4426950408889634f
#define SL_F (0.17677669529663687f * 1.4426950408889634f)   // SCALE*log2e

typedef unsigned short bfr;    // raw bf16 bits
typedef float floatx4 __attribute__((ext_vector_type(4)));
typedef float f32x4 __attribute__((ext_vector_type(4)));
typedef short bf16x8 __attribute__((ext_vector_type(8)));   // 8 bf16 = 1 b128
typedef short short4v __attribute__((ext_vector_type(4)));  // 4 bf16 = 1 b64

union B8 { floatx4 v; bfr h[8]; };

__device__ __forceinline__ float b2f(bfr u) {
    union { unsigned int i; float f; } v;
    v.i = (unsigned int)u << 16;
    return v.f;
}
__device__ __forceinline__ bfr f2b(float f) {
    union { float f; unsigned int i; } v;
    v.f = f;
    unsigned int x = v.i;
    return (bfr)((x + 0x7fffu + ((x >> 16) & 1u)) >> 16);  // RNE
}
// packed f32x2 -> bf16x2 (RNE), single instruction
__device__ __forceinline__ unsigned cvt_pk2(float lo, float hi) {
    unsigned r;
    asm("v_cvt_pk_bf16_f32 %0, %1, %2" : "=v"(r) : "v"(lo), "v"(hi));
    return r;
}

// diagnostic: encode ws_size (MiB) into the output if ws is too small
__global__ void fill_code(float* out, float code) {
    for (size_t i = (size_t)blockIdx.x*256 + threadIdx.x; i < (size_t)NB*PERB;
         i += (size_t)gridDim.x*256) out[i] = code;
}

// ---------------------------------------------------------------------------
// Kernel 1: QKV GEMM, MFMA. grid (9 o-tiles FAST, 256 s-tiles), 256 threads.
// ---------------------------------------------------------------------------
__global__ __launch_bounds__(256) void qkv_mfma(
    const float* __restrict__ x, const float* __restrict__ w,
    const float* __restrict__ bias,
    bfr* __restrict__ qT, bfr* __restrict__ kT, bfr* __restrict__ vT, int b)
{
    __shared__ __attribute__((aligned(16))) bfr wl[128*40];   // [o][c] pad40
    __shared__ __attribute__((aligned(16))) bfr xl[128*40];   // [s][c] pad40
    __shared__ float bsh[128];
    const int tid  = threadIdx.x;
    const int lane = tid & 63;
    const int wave = tid >> 6;
    const int wo   = (wave & 1) * 64;     // wave o-quadrant
    const int wsq  = (wave >> 1) * 64;    // wave s-quadrant
    const int s0   = blockIdx.y * 128;    // R8: swapped
    const int o0   = blockIdx.x * 128;    // R8: swapped (fast dim)
    const int m16  = lane & 15;           // fragment row/col index
    const int g    = lane >> 4;           // k-chunk quarter (0..3)

    if (tid < 128) bsh[tid] = bias[o0 + tid];

    f32x4 acc[4][4];
    #pragma unroll
    for (int i = 0; i < 4; ++i)
        #pragma unroll
        for (int j = 0; j < 4; ++j) acc[i][j] = (f32x4){0.f, 0.f, 0.f, 0.f};

    for (int kc = 0; kc < 12; ++kc) {
        const int c0 = kc * 32;
        // stage w tile [128 o][32 c] f32->bf16 (1024 float4, 4 per thread)
        #pragma unroll
        for (int r = 0; r < 4; ++r) {
            const int idx = r*256 + tid;
            const int o   = idx >> 3;
            const int c4  = (idx & 7) * 4;
            floatx4 wv = *(const floatx4*)&w[(size_t)(o0 + o)*NC + c0 + c4];
            short4v t;
            t[0] = (short)f2b(wv[0]); t[1] = (short)f2b(wv[1]);
            t[2] = (short)f2b(wv[2]); t[3] = (short)f2b(wv[3]);
            *(short4v*)&wl[o*40 + c4] = t;
        }
        // stage x tile transposed: [32 c][128 s] f32 -> LDS [s][c] bf16
        #pragma unroll
        for (int r = 0; r < 4; ++r) {
            const int idx = r*256 + tid;
            const int c   = idx >> 5;
            const int s4  = (idx & 31) * 4;
            floatx4 xv =
                *(const floatx4*)&x[((size_t)b*NC + c0 + c)*NS + s0 + s4];
            #pragma unroll
            for (int i = 0; i < 4; ++i) xl[(s4 + i)*40 + c] = f2b(xv[i]);
        }
        __syncthreads();
        bf16x8 af[4], bfg[4];
        #pragma unroll
        for (int i = 0; i < 4; ++i)
            af[i] = *(bf16x8*)&wl[(wo + i*16 + m16)*40 + g*8];
        #pragma unroll
        for (int j = 0; j < 4; ++j)
            bfg[j] = *(bf16x8*)&xl[(wsq + j*16 + m16)*40 + g*8];
        #pragma unroll
        for (int i = 0; i < 4; ++i)
            #pragma unroll
            for (int j = 0; j < 4; ++j)
                acc[i][j] = __builtin_amdgcn_mfma_f32_16x16x32_bf16(
                    af[i], bfg[j], acc[i][j], 0, 0, 0);
        __syncthreads();
    }

    // epilogue: +bias, bf16, heads layout. tensor uniform per block.
    const int tens = blockIdx.x / 3;            // 0=q,1=k,2=v
    bfr* dstT = (tens == 0) ? qT : ((tens == 1) ? kT : vT);
    const int remb = o0 - tens*NC;              // o offset within tensor
    const int q4   = g * 4;                     // C-layout row group
    #pragma unroll
    for (int i = 0; i < 4; ++i) {
        const int olb = wo + i*16 + q4;         // block-local o (mult of 4)
        const int ob  = remb + olb;
        const int hh  = ob >> 5;
        const int cc  = ob & 31;
        #pragma unroll
        for (int j = 0; j < 4; ++j) {
            const int s = s0 + wsq + j*16 + m16;
            short4v t;
            #pragma unroll
            for (int r = 0; r < 4; ++r)
                t[r] = (short)f2b(acc[i][j][r] + bsh[olb + r]);
            *(short4v*)&dstT[((size_t)hh*NS + s)*NHD + cc] = t;
        }
    }
}

// ---------------------------------------------------------------------------
// Kernel 2: attn3d — R8. grid (512 tiles, 12 heads), 256 threads.
// ---------------------------------------------------------------------------
__global__ __launch_bounds__(256, 4) void attn3d(
    const bfr* __restrict__ qT, const bfr* __restrict__ kT,
    const bfr* __restrict__ vT, const float* __restrict__ pe,
    bfr* __restrict__ aT)
{
    // exact-fit 40960 B -> 4 blocks/CU
    __shared__ __attribute__((aligned(16))) unsigned char smem[40960];
    bfr (*kl)[40]   = reinterpret_cast<bfr(*)[40]>(smem);          // [128][40]
    bfr (*vtl)[136] = reinterpret_cast<bfr(*)[136]>(smem + 10240); // [32][136]
    bfr (*pel)[40]  = reinterpret_cast<bfr(*)[40]>(smem);          // overlay
    bfr (*ql)[40]   = reinterpret_cast<bfr(*)[40]>(smem + 18944);  // [64][40]
    bfr (*qpl)[132] = reinterpret_cast<bfr(*)[132]>(smem + 24064); // [64][132]

    const int tid  = threadIdx.x;
    const int lane = tid & 63;
    const int wave = tid >> 6;            // wave = qz within tile
    const int m16  = lane & 15;
    const int g    = lane >> 4;
    const int g4   = g << 2;
    const int bx   = blockIdx.x;
    const int tz = bx >> 6, ty = (bx >> 3) & 7, tx = bx & 7;
    const size_t hb = (size_t)blockIdx.y * NS;

    // ---- stage Q tile (one b128 per thread) ----
    {
        const int qr = tid >> 2, part = tid & 3;
        const int qzr = qr >> 4, qyr = (qr >> 2) & 3, qxr = qr & 3;
        const size_t sq =
            (size_t)(tz*4 + qzr)*1024 + (ty*4 + qyr)*32 + (tx*4 + qxr);
        *(floatx4*)&ql[qr][part*8] =
            *(const floatx4*)&qT[(hb + sq)*NHD + part*8];
    }
    // ---- stage pe transposed into overlay: pe[hd*125+n] -> pel[n][hd] ----
    for (int e = tid; e < 4000; e += 256) {
        const int hd = e / 125;
        const int n  = e - hd*125;
        pel[n][hd] = f2b(pe[e]);
    }
    if (tid < 96) pel[125 + (tid >> 5)][tid & 31] = 0;
    __syncthreads();

    const int wq = wave*16 + m16;                 // this lane's query row
    const bf16x8 bq = *(const bf16x8*)&ql[wq][g*8];

    // ---- QPE^T[n][q] = PE . Q^T, pre-scaled by SCALE*log2e -> qpl[q][n] ----
    #pragma unroll
    for (int t = 0; t < 8; ++t) {
        bf16x8 pa = *(const bf16x8*)&pel[t*16 + m16][g*8];
        f32x4 qa = __builtin_amdgcn_mfma_f32_16x16x32_bf16(
            pa, bq, (f32x4){0.f, 0.f, 0.f, 0.f}, 0, 0, 0);
        const unsigned w0 = cvt_pk2(qa[0]*SL_F, qa[1]*SL_F);
        const unsigned w1 = cvt_pk2(qa[2]*SL_F, qa[3]*SL_F);
        *(uint2*)&qpl[wq][t*16 + g4] = make_uint2(w0, w1);
    }

    // ---- per-lane tables: gather offsets (elements) + mask floats ----
    const int qy = m16 >> 2, qx = m16 & 3;
    int   noff[16];
    float maskf[16];
    #pragma unroll
    for (int tt = 0; tt < 4; ++tt) {
        #pragma unroll
        for (int r = 0; r < 4; ++r) {
            const int t0 = g4 + r;
            const int hy = 2*tt + (t0 >> 3), hx = t0 & 7;
            const int dy = hy - qy, dx = hx - qx;
            const bool ok = ((unsigned)dy < 5u) && ((unsigned)dx < 5u);
            noff[tt*4 + r]  = ok ? (dy*5 + dx) : 0;   // in-range garbage if !ok
            maskf[tt*4 + r] = ok ? 1.f : 0.f;
        }
    }
    const bfr* qprow = qpl[wq];
    // bpermute byte-addrs for P redistribution
    const int a0 = (m16 + 32*(g & 1)) * 4;
    const int a1 = a0 + 64;
    const bool ghi = (g >= 2);

    float m = -1e30f, l = 0.f;
    f32x4 o[2];
    o[0] = (f32x4){0.f, 0.f, 0.f, 0.f};
    o[1] = (f32x4){0.f, 0.f, 0.f, 0.f};

    // ---- async staging registers + per-thread load mappings ----
    const int kkey0 = tid >> 2, kpart = tid & 3;   // K: 2 rows/thread
    const int kkey1 = kkey0 + 64;
    const int vkp   = tid & 63, vhdo = tid >> 6;   // V: key pair/thread
    const int vaK   = 2*vkp;
    floatx4 kst0, kst1;
    B8 vsa, vsb;

    auto kload = [&](int key, int c) -> floatx4 {
        const int hz = key >> 6, hy = (key >> 3) & 7, hx = key & 7;
        const int gz = tz*4 - 2 + 2*c + hz, gy = ty*4 - 2 + hy,
                  gx = tx*4 - 2 + hx;
        if ((unsigned)gz < 32u && (unsigned)gy < 32u && (unsigned)gx < 32u)
            return *(const floatx4*)
                   &kT[(hb + gz*1024 + gy*32 + gx)*NHD + kpart*8];
        return (floatx4){0.f, 0.f, 0.f, 0.f};
    };
    auto vload = [&](int c) {
        const int hz = vaK >> 6, hy = (vaK >> 3) & 7, hx = vaK & 7;
        const int gz = tz*4 - 2 + 2*c + hz, gy = ty*4 - 2 + hy,
                  gx = tx*4 - 2 + hx;
        const bool vzy = ((unsigned)gz < 32u) && ((unsigned)gy < 32u);
        vsa.v = (floatx4){0.f, 0.f, 0.f, 0.f};
        vsb.v = (floatx4){0.f, 0.f, 0.f, 0.f};
        const size_t gb = hb + gz*1024 + gy*32;
        if (vzy && (unsigned)gx < 32u)
            vsa.v = *(const floatx4*)&vT[(gb + gx)*NHD + vhdo*8];
        if (vzy && (unsigned)(gx + 1) < 32u)
            vsb.v = *(const floatx4*)&vT[(gb + gx + 1)*NHD + vhdo*8];
    };

    kst0 = kload(kkey0, 0);
    kst1 = kload(kkey1, 0);
    vload(0);

    for (int c = 0; c < 4; ++c) {
        __syncthreads();   // prev-chunk reads (and pel/QPE reads for c=0) done
        // ---- write staged chunk to LDS ----
        *(floatx4*)&kl[kkey0][kpart*8] = kst0;
        *(floatx4*)&kl[kkey1][kpart*8] = kst1;
        #pragma unroll
        for (int i = 0; i < 8; ++i) {
            const unsigned u = (unsigned)vsa.h[i] | ((unsigned)vsb.h[i] << 16);
            *(unsigned*)&vtl[vhdo*8 + i][vaK] = u;
        }
        __syncthreads();   // chunk staged
        // ---- issue next chunk's global loads (latency hides under compute) --
        if (c < 3) {
            kst0 = kload(kkey0, c + 1);
            kst1 = kload(kkey1, c + 1);
            vload(c + 1);
        }

        #pragma unroll
        for (int zl = 0; zl < 2; ++zl) {
            const int dz = 2*c + zl - wave;       // wave-uniform
            if ((unsigned)dz > 4u) continue;      // skip invalid z layer
            // ---- S^T tile = K . Q^T (4 MFMAs, 64 keys) ----
            f32x4 s[4];
            __builtin_amdgcn_s_setprio(1);
            #pragma unroll
            for (int tt = 0; tt < 4; ++tt) {
                bf16x8 ka = *(const bf16x8*)&kl[zl*64 + tt*16 + m16][g*8];
                s[tt] = __builtin_amdgcn_mfma_f32_16x16x32_bf16(
                    ka, bq, (f32x4){0.f, 0.f, 0.f, 0.f}, 0, 0, 0);
            }
            __builtin_amdgcn_s_setprio(0);
            // ---- biased scores (log2 domain) + layer max (mask deferred) ----
            const bfr* qb_l = qprow + dz*25;
            float mx = -1e30f;
            #pragma unroll
            for (int tt = 0; tt < 4; ++tt) {
                const float v0 = fmaf(s[tt][0], SL_F, b2f(qb_l[noff[tt*4+0]]));
                const float v1 = fmaf(s[tt][1], SL_F, b2f(qb_l[noff[tt*4+1]]));
                const float v2 = fmaf(s[tt][2], SL_F, b2f(qb_l[noff[tt*4+2]]));
                const float v3 = fmaf(s[tt][3], SL_F, b2f(qb_l[noff[tt*4+3]]));
                s[tt][0] = v0; s[tt][1] = v1; s[tt][2] = v2; s[tt][3] = v3;
                mx = fmaxf(fmaxf(fmaxf(v0, v1), fmaxf(v2, v3)), mx);
            }
            mx = fmaxf(mx, __shfl_xor(mx, 16));
            mx = fmaxf(mx, __shfl_xor(mx, 32));
            const float mn = fmaxf(m, mx);
            const float al = exp2f(m - mn);
            m = mn;
            // ---- P = exp2(S - m) * mask, packed bf16 via cvt_pk ----
            float ls = 0.f;
            unsigned pk[4][2];
            #pragma unroll
            for (int tt = 0; tt < 4; ++tt) {
                const float p0 = exp2f(s[tt][0] - mn) * maskf[tt*4+0];
                const float p1 = exp2f(s[tt][1] - mn) * maskf[tt*4+1];
                const float p2 = exp2f(s[tt][2] - mn) * maskf[tt*4+2];
                const float p3 = exp2f(s[tt][3] - mn) * maskf[tt*4+3];
                ls += (p0 + p1) + (p2 + p3);
                pk[tt][0] = cvt_pk2(p0, p1);
                pk[tt][1] = cvt_pk2(p2, p3);
            }
            ls += __shfl_xor(ls, 16);
            ls += __shfl_xor(ls, 32);
            l = l * al + ls;
            #pragma unroll
            for (int i = 0; i < 4; ++i) { o[0][i] *= al; o[1][i] *= al; }
            // ---- O^T += V^T . P^T; P B-frag via bpermute ----
            #pragma unroll
            for (int ksl = 0; ksl < 2; ++ksl) {
                union { unsigned u[4]; bf16x8 v; } pb;
                #pragma unroll
                for (int w = 0; w < 4; ++w) {
                    const int ad = (w < 2) ? a0 : a1;
                    const int wi = w & 1;
                    const int lo = __builtin_amdgcn_ds_bpermute(
                        ad, (int)pk[2*ksl][wi]);
                    const int hi = __builtin_amdgcn_ds_bpermute(
                        ad, (int)pk[2*ksl + 1][wi]);
                    pb.u[w] = ghi ? (unsigned)hi : (unsigned)lo;
                }
                __builtin_amdgcn_s_setprio(1);
                #pragma unroll
                for (int mt = 0; mt < 2; ++mt) {
                    bf16x8 va = *(const bf16x8*)
                        &vtl[mt*16 + m16][zl*64 + ksl*32 + g*8];
                    o[mt] = __builtin_amdgcn_mfma_f32_16x16x32_bf16(
                        va, pb.v, o[mt], 0, 0, 0);
                }
                __builtin_amdgcn_s_setprio(0);
            }
        }
    }

    // ---- normalize + store: lane holds O^T[hd = mt*16+g4+r][q = wq] ----
    const float rl = 1.f / l;
    const size_t sq = (size_t)(tz*4 + wave)*1024 + (ty*4 + qy)*32 + (tx*4 + qx);
    #pragma unroll
    for (int mt = 0; mt < 2; ++mt) {
        const unsigned w0 = cvt_pk2(o[mt][0]*rl, o[mt][1]*rl);
        const unsigned w1 = cvt_pk2(o[mt][2]*rl, o[mt][3]*rl);
        *(uint2*)&aT[(hb + sq)*NHD + mt*16 + g4] = make_uint2(w0, w1);
    }
}

// ---------------------------------------------------------------------------
// Kernel 3: proj GEMM, MFMA. grid (3 o-tiles FAST, 256 s-tiles), 256 threads.
// ---------------------------------------------------------------------------
__global__ __launch_bounds__(256) void proj_mfma(
    const bfr* __restrict__ aT, const float* __restrict__ w,
    const float* __restrict__ bias, float* __restrict__ out)
{
    __shared__ __attribute__((aligned(16))) bfr wl[128*40];   // [o][c] pad40
    __shared__ __attribute__((aligned(16))) bfr xl[128*40];   // [s][c] pad40
    __shared__ float bsh[128];
    const int tid  = threadIdx.x;
    const int lane = tid & 63;
    const int wave = tid >> 6;
    const int wo   = (wave & 1) * 64;
    const int wsq  = (wave >> 1) * 64;
    const int s0   = blockIdx.y * 128;    // R8: swapped
    const int o0   = blockIdx.x * 128;    // R8: swapped (fast dim)
    const int m16  = lane & 15;
    const int g    = lane >> 4;

    if (tid < 128) bsh[tid] = bias[o0 + tid];

    f32x4 acc[4][4];
    #pragma unroll
    for (int i = 0; i < 4; ++i)
        #pragma unroll
        for (int j = 0; j < 4; ++j) acc[i][j] = (f32x4){0.f, 0.f, 0.f, 0.f};

    for (int kc = 0; kc < 12; ++kc) {          // kc == head
        const int c0 = kc * 32;
        // stage w tile [128 o][32 c] f32->bf16
        #pragma unroll
        for (int r = 0; r < 4; ++r) {
            const int idx = r*256 + tid;
            const int o   = idx >> 3;
            const int c4  = (idx & 7) * 4;
            floatx4 wv = *(const floatx4*)&w[(size_t)(o0 + o)*NC + c0 + c4];
            short4v t;
            t[0] = (short)f2b(wv[0]); t[1] = (short)f2b(wv[1]);
            t[2] = (short)f2b(wv[2]); t[3] = (short)f2b(wv[3]);
            *(short4v*)&wl[o*40 + c4] = t;
        }
        // stage a tile: [128 s][32 c] bf16, direct b128 copies (512, 2/thread)
        #pragma unroll
        for (int r = 0; r < 2; ++r) {
            const int idx = r*256 + tid;
            const int s   = idx >> 2;
            const int gg  = idx & 3;
            *(floatx4*)&xl[s*40 + gg*8] =
                *(const floatx4*)&aT[((size_t)kc*NS + s0 + s)*NHD + gg*8];
        }
        __syncthreads();
        bf16x8 af[4], bfg[4];
        #pragma unroll
        for (int i = 0; i < 4; ++i)
            af[i] = *(bf16x8*)&wl[(wo + i*16 + m16)*40 + g*8];
        #pragma unroll
        for (int j = 0; j < 4; ++j)
            bfg[j] = *(bf16x8*)&xl[(wsq + j*16 + m16)*40 + g*8];
        #pragma unroll
        for (int i = 0; i < 4; ++i)
            #pragma unroll
            for (int j = 0; j < 4; ++j)
                acc[i][j] = __builtin_amdgcn_mfma_f32_16x16x32_bf16(
                    af[i], bfg[j], acc[i][j], 0, 0, 0);
        __syncthreads();
    }

    // epilogue: +bias, f32 channel-major out[o][s]
    const int q4 = g * 4;
    #pragma unroll
    for (int i = 0; i < 4; ++i) {
        const int olb = wo + i*16 + q4;
        #pragma unroll
        for (int j = 0; j < 4; ++j) {
            const int s = s0 + wsq + j*16 + m16;
            #pragma unroll
            for (int r = 0; r < 4; ++r)
                out[(size_t)(o0 + olb + r)*NS + s] = acc[i][j][r] + bsh[olb + r];
        }
    }
}

// ---------------------------------------------------------------------------
extern "C" void kernel_launch(void* const* d_in, const int* in_sizes, int n_in,
                              void* d_out, int out_size, void* d_ws, size_t ws_size,
                              hipStream_t stream)
{
    const float* x      = (const float*)d_in[0];
    const float* w_qkv  = (const float*)d_in[1];
    const float* b_qkv  = (const float*)d_in[2];
    const float* w_proj = (const float*)d_in[3];
    const float* b_proj = (const float*)d_in[4];
    const float* pe     = (const float*)d_in[5];
    float* outp = (float*)d_out;

    const size_t NEED = (size_t)2 * PERB * sizeof(bfr);  // 48 MiB
    if (ws_size < NEED) {
        fill_code<<<2048, 256, 0, stream>>>(outp, (float)(ws_size >> 20));
        return;
    }

    bfr* qT = (bfr*)d_ws;          // ws[0 .. PERB)      (aT aliases this)
    bfr* vT = qT + PERB;           // ws[PERB .. 2*PERB)

    for (int b = 0; b < NB; ++b) {
        bfr* kT = (bfr*)(outp + (size_t)b * PERB);  // d_out batch half
        bfr* aT = qT;
        qkv_mfma<<<dim3(9, 256, 1), 256, 0, stream>>>(
            x, w_qkv, b_qkv, qT, kT, vT, b);
        attn3d<<<dim3(512, 12, 1), 256, 0, stream>>>(qT, kT, vT, pe, aT);
        proj_mfma<<<dim3(3, 256, 1), 256, 0, stream>>>(
            aT, w_proj, b_proj, outp + (size_t)b * PERB);
    }
}

// Round 4
// 699.828 us; speedup vs baseline: 1.0348x; 1.0348x over previous
//
#include <hip/hip_runtime.h>

// ---------------------------------------------------------------------------
// SpatialAttention3D: B=2, C=384, D=H=W=32, HEADS=12, HD=32, WS=5, PAD=2
// I/O dtype: float32. Intermediates q/k/v/a: bf16.
// R9 = R7 attn3d structure (no spills) + the two R8 changes that worked:
//   - attn3d: packed nopk u8 gather + min-sentinel mask (4 regs, not 32),
//     direct K/V staging (no persistent staging regs -> no scratch spill),
//     v_cvt_pk_bf16_f32 packing, T13 defer-rescale (__any-guarded, exact).
//   - qkv/proj: grid dims swapped (o-tile fastest) for x/a L2/L3 reuse;
//     cvt_pk2 in w-staging + qkv epilogue packs.
// R8 post-mortem: noff[16]+maskf[16]+4 staging regs under launch_bounds(256,4)
// spilled to scratch (WRITE_SIZE 24.6->178 MB). Reverted.
// ---------------------------------------------------------------------------

#define NB 2
#define NC 384
#define NHEADS 12
#define NHD 32
#define NS 32768               // 32*32*32
#define PERB 12582912          // NC*NS (one batch of out / qkv third)
#define SCALE_F 0.17677669529663687f
#define LOG2E_F 1.4426950408889634f
#define SL_F (0.17677669529663687f * 1.4426950408889634f)   // SCALE*log2e

typedef unsigned short bfr;    // raw bf16 bits
typedef float floatx4 __attribute__((ext_vector_type(4)));
typedef float f32x4 __attribute__((ext_vector_type(4)));
typedef short bf16x8 __attribute__((ext_vector_type(8)));   // 8 bf16 = 1 b128
typedef short short4v __attribute__((ext_vector_type(4)));  // 4 bf16 = 1 b64

union B8 { floatx4 v; bfr h[8]; };

__device__ __forceinline__ float b2f(bfr u) {
    union { unsigned int i; float f; } v;
    v.i = (unsigned int)u << 16;
    return v.f;
}
__device__ __forceinline__ bfr f2b(float f) {
    union { float f; unsigned int i; } v;
    v.f = f;
    unsigned int x = v.i;
    return (bfr)((x + 0x7fffu + ((x >> 16) & 1u)) >> 16);  // RNE
}
// packed f32x2 -> bf16x2 (RNE), single instruction
__device__ __forceinline__ unsigned cvt_pk2(float lo, float hi) {
    unsigned r;
    asm("v_cvt_pk_bf16_f32 %0, %1, %2" : "=v"(r) : "v"(lo), "v"(hi));
    return r;
}

// diagnostic: encode ws_size (MiB) into the output if ws is too small
__global__ void fill_code(float* out, float code) {
    for (size_t i = (size_t)blockIdx.x*256 + threadIdx.x; i < (size_t)NB*PERB;
         i += (size_t)gridDim.x*256) out[i] = code;
}

// ---------------------------------------------------------------------------
// Kernel 1: QKV GEMM, MFMA. grid (9 o-tiles FAST, 256 s-tiles), 256 threads.
// ---------------------------------------------------------------------------
__global__ __launch_bounds__(256) void qkv_mfma(
    const float* __restrict__ x, const float* __restrict__ w,
    const float* __restrict__ bias,
    bfr* __restrict__ qT, bfr* __restrict__ kT, bfr* __restrict__ vT, int b)
{
    __shared__ __attribute__((aligned(16))) bfr wl[128*40];   // [o][c] pad40
    __shared__ __attribute__((aligned(16))) bfr xl[128*40];   // [s][c] pad40
    __shared__ float bsh[128];
    const int tid  = threadIdx.x;
    const int lane = tid & 63;
    const int wave = tid >> 6;
    const int wo   = (wave & 1) * 64;     // wave o-quadrant
    const int wsq  = (wave >> 1) * 64;    // wave s-quadrant
    const int s0   = blockIdx.y * 128;
    const int o0   = blockIdx.x * 128;    // fast dim: 9 o-tiles share s-tile
    const int m16  = lane & 15;           // fragment row/col index
    const int g    = lane >> 4;           // k-chunk quarter (0..3)

    if (tid < 128) bsh[tid] = bias[o0 + tid];

    f32x4 acc[4][4];
    #pragma unroll
    for (int i = 0; i < 4; ++i)
        #pragma unroll
        for (int j = 0; j < 4; ++j) acc[i][j] = (f32x4){0.f, 0.f, 0.f, 0.f};

    for (int kc = 0; kc < 12; ++kc) {
        const int c0 = kc * 32;
        // stage w tile [128 o][32 c] f32->bf16 (1024 float4, 4 per thread)
        #pragma unroll
        for (int r = 0; r < 4; ++r) {
            const int idx = r*256 + tid;
            const int o   = idx >> 3;
            const int c4  = (idx & 7) * 4;
            floatx4 wv = *(const floatx4*)&w[(size_t)(o0 + o)*NC + c0 + c4];
            *(uint2*)&wl[o*40 + c4] =
                make_uint2(cvt_pk2(wv[0], wv[1]), cvt_pk2(wv[2], wv[3]));
        }
        // stage x tile transposed: [32 c][128 s] f32 -> LDS [s][c] bf16
        #pragma unroll
        for (int r = 0; r < 4; ++r) {
            const int idx = r*256 + tid;
            const int c   = idx >> 5;
            const int s4  = (idx & 31) * 4;
            floatx4 xv =
                *(const floatx4*)&x[((size_t)b*NC + c0 + c)*NS + s0 + s4];
            #pragma unroll
            for (int i = 0; i < 4; ++i) xl[(s4 + i)*40 + c] = f2b(xv[i]);
        }
        __syncthreads();
        bf16x8 af[4], bfg[4];
        #pragma unroll
        for (int i = 0; i < 4; ++i)
            af[i] = *(bf16x8*)&wl[(wo + i*16 + m16)*40 + g*8];
        #pragma unroll
        for (int j = 0; j < 4; ++j)
            bfg[j] = *(bf16x8*)&xl[(wsq + j*16 + m16)*40 + g*8];
        #pragma unroll
        for (int i = 0; i < 4; ++i)
            #pragma unroll
            for (int j = 0; j < 4; ++j)
                acc[i][j] = __builtin_amdgcn_mfma_f32_16x16x32_bf16(
                    af[i], bfg[j], acc[i][j], 0, 0, 0);
        __syncthreads();
    }

    // epilogue: +bias, bf16, heads layout. tensor uniform per block.
    const int tens = blockIdx.x / 3;            // 0=q,1=k,2=v
    bfr* dstT = (tens == 0) ? qT : ((tens == 1) ? kT : vT);
    const int remb = o0 - tens*NC;              // o offset within tensor
    const int q4   = g * 4;                     // C-layout row group
    #pragma unroll
    for (int i = 0; i < 4; ++i) {
        const int olb = wo + i*16 + q4;         // block-local o (mult of 4)
        const int ob  = remb + olb;
        const int hh  = ob >> 5;
        const int cc  = ob & 31;
        #pragma unroll
        for (int j = 0; j < 4; ++j) {
            const int s = s0 + wsq + j*16 + m16;
            const unsigned u0 = cvt_pk2(acc[i][j][0] + bsh[olb + 0],
                                        acc[i][j][1] + bsh[olb + 1]);
            const unsigned u1 = cvt_pk2(acc[i][j][2] + bsh[olb + 2],
                                        acc[i][j][3] + bsh[olb + 3]);
            *(uint2*)&dstT[((size_t)hh*NS + s)*NHD + cc] = make_uint2(u0, u1);
        }
    }
}

// ---------------------------------------------------------------------------
// Kernel 2: attn3d — R9 (R7 structure + cvt_pk + T13). grid (512, 12), 256 th.
// ---------------------------------------------------------------------------
__global__ __launch_bounds__(256, 4) void attn3d(
    const bfr* __restrict__ qT, const bfr* __restrict__ kT,
    const bfr* __restrict__ vT, const float* __restrict__ pe,
    bfr* __restrict__ aT)
{
    // exact-fit 40960 B -> 4 blocks/CU
    __shared__ __attribute__((aligned(16))) unsigned char smem[40960];
    bfr (*kl)[40]   = reinterpret_cast<bfr(*)[40]>(smem);          // [128][40]
    bfr (*vtl)[136] = reinterpret_cast<bfr(*)[136]>(smem + 10240); // [32][136]
    bfr (*pel)[40]  = reinterpret_cast<bfr(*)[40]>(smem);          // overlay
    bfr (*ql)[40]   = reinterpret_cast<bfr(*)[40]>(smem + 18944);  // [64][40]
    bfr (*qpl)[132] = reinterpret_cast<bfr(*)[132]>(smem + 24064); // [64][132]

    const int tid  = threadIdx.x;
    const int lane = tid & 63;
    const int wave = tid >> 6;            // wave = qz within tile
    const int m16  = lane & 15;
    const int g    = lane >> 4;
    const int g4   = g << 2;
    const int bx   = blockIdx.x;
    const int tz = bx >> 6, ty = (bx >> 3) & 7, tx = bx & 7;
    const size_t hb = (size_t)blockIdx.y * NS;

    // ---- stage Q tile (one b128 per thread) ----
    {
        const int qr = tid >> 2, part = tid & 3;
        const int qzr = qr >> 4, qyr = (qr >> 2) & 3, qxr = qr & 3;
        const size_t sq =
            (size_t)(tz*4 + qzr)*1024 + (ty*4 + qyr)*32 + (tx*4 + qxr);
        *(floatx4*)&ql[qr][part*8] =
            *(const floatx4*)&qT[(hb + sq)*NHD + part*8];
    }
    // ---- stage pe transposed into overlay: pe[hd*125+n] -> pel[n][hd] ----
    for (int e = tid; e < 4000; e += 256) {
        const int hd = e / 125;
        const int n  = e - hd*125;
        pel[n][hd] = f2b(pe[e]);
    }
    if (tid < 96) pel[125 + (tid >> 5)][tid & 31] = 0;
    __syncthreads();

    const int wq = wave*16 + m16;                 // this lane's query row
    const bf16x8 bq = *(const bf16x8*)&ql[wq][g*8];

    // ---- QPE^T[n][q] = PE . Q^T, pre-scaled by SCALE*log2e -> qpl[q][n] ----
    #pragma unroll
    for (int t = 0; t < 8; ++t) {
        bf16x8 pa = *(const bf16x8*)&pel[t*16 + m16][g*8];
        f32x4 qa = __builtin_amdgcn_mfma_f32_16x16x32_bf16(
            pa, bq, (f32x4){0.f, 0.f, 0.f, 0.f}, 0, 0, 0);
        const unsigned w0 = cvt_pk2(qa[0]*SL_F, qa[1]*SL_F);
        const unsigned w1 = cvt_pk2(qa[2]*SL_F, qa[3]*SL_F);
        *(uint2*)&qpl[wq][t*16 + g4] = make_uint2(w0, w1);
    }
    if (g == 0) qpl[wq][128] = 0xFF80u;           // -inf sentinel column

    // ---- per-lane window table no[tt][r], packed 4x u8 per reg ----
    const int qy = m16 >> 2, qx = m16 & 3;
    unsigned nopk[4];
    #pragma unroll
    for (int tt = 0; tt < 4; ++tt) {
        unsigned v = 0;
        #pragma unroll
        for (int r = 0; r < 4; ++r) {
            const int t0 = g4 + r;
            const int hy = 2*tt + (t0 >> 3), hx = t0 & 7;
            const int dy = hy - qy, dx = hx - qx;
            const bool ok = ((unsigned)dy < 5u) && ((unsigned)dx < 5u);
            v |= (unsigned)(ok ? (dy*5 + dx) : 128) << (8*r);
        }
        nopk[tt] = v;
    }
    const bfr* qprow = qpl[wq];
    // bpermute byte-addrs for P redistribution
    const int a0 = (m16 + 32*(g & 1)) * 4;
    const int a1 = a0 + 64;
    const bool ghi = (g >= 2);

    float m = -1e30f, l = 0.f;
    f32x4 o[2];
    o[0] = (f32x4){0.f, 0.f, 0.f, 0.f};
    o[1] = (f32x4){0.f, 0.f, 0.f, 0.f};

    for (int c = 0; c < 4; ++c) {
        __syncthreads();   // prev-chunk reads (and pel/QPE reads for c=0) done
        // ---- stage K chunk: 128 keys x 32 c, zero-padded OOB ----
        #pragma unroll
        for (int r2 = 0; r2 < 2; ++r2) {
            const int idx = r2*256 + tid;
            const int key = idx >> 2, part = idx & 3;
            const int hz = key >> 6, hy = (key >> 3) & 7, hx = key & 7;
            const int gz = tz*4 - 2 + 2*c + hz, gy = ty*4 - 2 + hy,
                      gx = tx*4 - 2 + hx;
            floatx4 kv = (floatx4){0.f, 0.f, 0.f, 0.f};
            if ((unsigned)gz < 32u && (unsigned)gy < 32u && (unsigned)gx < 32u)
                kv = *(const floatx4*)
                     &kT[(hb + gz*1024 + gy*32 + gx)*NHD + part*8];
            *(floatx4*)&kl[key][part*8] = kv;
        }
        // ---- stage V^T chunk: key-pair packed b32 writes (conflict-free) ----
        {
            const int kp = tid & 63, hdo = tid >> 6;
            const int aK = 2*kp;                 // even key; pair never
            const int hz = aK >> 6;              // straddles a halo row
            const int hy = (aK >> 3) & 7, hx = aK & 7;
            const int gz = tz*4 - 2 + 2*c + hz, gy = ty*4 - 2 + hy,
                      gx = tx*4 - 2 + hx;
            const bool vzy = ((unsigned)gz < 32u) && ((unsigned)gy < 32u);
            B8 va, vb;
            va.v = (floatx4){0.f, 0.f, 0.f, 0.f};
            vb.v = (floatx4){0.f, 0.f, 0.f, 0.f};
            const size_t gb = hb + gz*1024 + gy*32;
            if (vzy && (unsigned)gx < 32u)
                va.v = *(const floatx4*)&vT[(gb + gx)*NHD + hdo*8];
            if (vzy && (unsigned)(gx + 1) < 32u)
                vb.v = *(const floatx4*)&vT[(gb + gx + 1)*NHD + hdo*8];
            #pragma unroll
            for (int i = 0; i < 8; ++i) {
                const unsigned u = (unsigned)va.h[i] | ((unsigned)vb.h[i] << 16);
                *(unsigned*)&vtl[hdo*8 + i][aK] = u;
            }
        }
        __syncthreads();   // chunk staged

        #pragma unroll
        for (int zl = 0; zl < 2; ++zl) {
            const int dz = 2*c + zl - wave;       // wave-uniform
            if ((unsigned)dz > 4u) continue;      // skip invalid z layer
            const int nz = dz * 25;
            // ---- S^T tile = K . Q^T (4 MFMAs, 64 keys) ----
            f32x4 s[4];
            __builtin_amdgcn_s_setprio(1);
            #pragma unroll
            for (int tt = 0; tt < 4; ++tt) {
                bf16x8 ka = *(const bf16x8*)&kl[zl*64 + tt*16 + m16][g*8];
                s[tt] = __builtin_amdgcn_mfma_f32_16x16x32_bf16(
                    ka, bq, (f32x4){0.f, 0.f, 0.f, 0.f}, 0, 0, 0);
            }
            __builtin_amdgcn_s_setprio(0);
            // ---- biased+masked scores (log2 domain), layer max ----
            float mx = -1e30f;
            #pragma unroll
            for (int tt = 0; tt < 4; ++tt) {
                #pragma unroll
                for (int r = 0; r < 4; ++r) {
                    const unsigned n =
                        min((unsigned)nz + ((nopk[tt] >> (8*r)) & 255u), 128u);
                    const float qb  = b2f(qprow[n]);   // -inf when masked
                    const float val = fmaf(s[tt][r], SL_F, qb);
                    s[tt][r] = val;
                    mx = fmaxf(mx, val);
                }
            }
            mx = fmaxf(mx, __shfl_xor(mx, 16));
            mx = fmaxf(mx, __shfl_xor(mx, 32));
            const float mn = fmaxf(m, mx);
            // ---- T13: rescale only if some lane's max grew (al==1 else) ----
            if (__any(mx > m)) {
                const float al = exp2f(m - mn);
                l *= al;
                #pragma unroll
                for (int i = 0; i < 4; ++i) { o[0][i] *= al; o[1][i] *= al; }
                m = mn;
            }
            // ---- P = exp2(S - m), bf16-packed via cvt_pk ----
            float ls = 0.f;
            unsigned pk[4][2];
            #pragma unroll
            for (int tt = 0; tt < 4; ++tt) {
                const float p0 = exp2f(s[tt][0] - m);
                const float p1 = exp2f(s[tt][1] - m);
                const float p2 = exp2f(s[tt][2] - m);
                const float p3 = exp2f(s[tt][3] - m);
                ls += (p0 + p1) + (p2 + p3);
                pk[tt][0] = cvt_pk2(p0, p1);
                pk[tt][1] = cvt_pk2(p2, p3);
            }
            ls += __shfl_xor(ls, 16);
            ls += __shfl_xor(ls, 32);
            l += ls;
            // ---- O^T += V^T . P^T; P B-frag via bpermute ----
            // lane (m16,g) needs P[q=m16][k=ksl*32+g*8+j]; src lane
            // m16+16*(2*(g&1)+(w>>1)), tile tt=2*ksl+(g>>1), word (w&1).
            #pragma unroll
            for (int ksl = 0; ksl < 2; ++ksl) {
                union { unsigned u[4]; bf16x8 v; } pb;
                #pragma unroll
                for (int w = 0; w < 4; ++w) {
                    const int ad = (w < 2) ? a0 : a1;
                    const int wi = w & 1;
                    const int lo = __builtin_amdgcn_ds_bpermute(
                        ad, (int)pk[2*ksl][wi]);
                    const int hi = __builtin_amdgcn_ds_bpermute(
                        ad, (int)pk[2*ksl + 1][wi]);
                    pb.u[w] = ghi ? (unsigned)hi : (unsigned)lo;
                }
                __builtin_amdgcn_s_setprio(1);
                #pragma unroll
                for (int mt = 0; mt < 2; ++mt) {
                    bf16x8 va = *(const bf16x8*)
                        &vtl[mt*16 + m16][zl*64 + ksl*32 + g*8];
                    o[mt] = __builtin_amdgcn_mfma_f32_16x16x32_bf16(
                        va, pb.v, o[mt], 0, 0, 0);
                }
                __builtin_amdgcn_s_setprio(0);
            }
        }
    }

    // ---- normalize + store: lane holds O^T[hd = mt*16+g4+r][q = wq] ----
    const float rl = 1.f / l;
    const size_t sq = (size_t)(tz*4 + wave)*1024 + (ty*4 + qy)*32 + (tx*4 + qx);
    #pragma unroll
    for (int mt = 0; mt < 2; ++mt) {
        const unsigned w0 = cvt_pk2(o[mt][0]*rl, o[mt][1]*rl);
        const unsigned w1 = cvt_pk2(o[mt][2]*rl, o[mt][3]*rl);
        *(uint2*)&aT[(hb + sq)*NHD + mt*16 + g4] = make_uint2(w0, w1);
    }
}

// ---------------------------------------------------------------------------
// Kernel 3: proj GEMM, MFMA. grid (3 o-tiles FAST, 256 s-tiles), 256 threads.
// ---------------------------------------------------------------------------
__global__ __launch_bounds__(256) void proj_mfma(
    const bfr* __restrict__ aT, const float* __restrict__ w,
    const float* __restrict__ bias, float* __restrict__ out)
{
    __shared__ __attribute__((aligned(16))) bfr wl[128*40];   // [o][c] pad40
    __shared__ __attribute__((aligned(16))) bfr xl[128*40];   // [s][c] pad40
    __shared__ float bsh[128];
    const int tid  = threadIdx.x;
    const int lane = tid & 63;
    const int wave = tid >> 6;
    const int wo   = (wave & 1) * 64;
    const int wsq  = (wave >> 1) * 64;
    const int s0   = blockIdx.y * 128;
    const int o0   = blockIdx.x * 128;    // fast dim
    const int m16  = lane & 15;
    const int g    = lane >> 4;

    if (tid < 128) bsh[tid] = bias[o0 + tid];

    f32x4 acc[4][4];
    #pragma unroll
    for (int i = 0; i < 4; ++i)
        #pragma unroll
        for (int j = 0; j < 4; ++j) acc[i][j] = (f32x4){0.f, 0.f, 0.f, 0.f};

    for (int kc = 0; kc < 12; ++kc) {          // kc == head
        const int c0 = kc * 32;
        // stage w tile [128 o][32 c] f32->bf16
        #pragma unroll
        for (int r = 0; r < 4; ++r) {
            const int idx = r*256 + tid;
            const int o   = idx >> 3;
            const int c4  = (idx & 7) * 4;
            floatx4 wv = *(const floatx4*)&w[(size_t)(o0 + o)*NC + c0 + c4];
            *(uint2*)&wl[o*40 + c4] =
                make_uint2(cvt_pk2(wv[0], wv[1]), cvt_pk2(wv[2], wv[3]));
        }
        // stage a tile: [128 s][32 c] bf16, direct b128 copies (512, 2/thread)
        #pragma unroll
        for (int r = 0; r < 2; ++r) {
            const int idx = r*256 + tid;
            const int s   = idx >> 2;
            const int gg  = idx & 3;
            *(floatx4*)&xl[s*40 + gg*8] =
                *(const floatx4*)&aT[((size_t)kc*NS + s0 + s)*NHD + gg*8];
        }
        __syncthreads();
        bf16x8 af[4], bfg[4];
        #pragma unroll
        for (int i = 0; i < 4; ++i)
            af[i] = *(bf16x8*)&wl[(wo + i*16 + m16)*40 + g*8];
        #pragma unroll
        for (int j = 0; j < 4; ++j)
            bfg[j] = *(bf16x8*)&xl[(wsq + j*16 + m16)*40 + g*8];
        #pragma unroll
        for (int i = 0; i < 4; ++i)
            #pragma unroll
            for (int j = 0; j < 4; ++j)
                acc[i][j] = __builtin_amdgcn_mfma_f32_16x16x32_bf16(
                    af[i], bfg[j], acc[i][j], 0, 0, 0);
        __syncthreads();
    }

    // epilogue: +bias, f32 channel-major out[o][s]
    const int q4 = g * 4;
    #pragma unroll
    for (int i = 0; i < 4; ++i) {
        const int olb = wo + i*16 + q4;
        #pragma unroll
        for (int j = 0; j < 4; ++j) {
            const int s = s0 + wsq + j*16 + m16;
            #pragma unroll
            for (int r = 0; r < 4; ++r)
                out[(size_t)(o0 + olb + r)*NS + s] = acc[i][j][r] + bsh[olb + r];
        }
    }
}

// ---------------------------------------------------------------------------
extern "C" void kernel_launch(void* const* d_in, const int* in_sizes, int n_in,
                              void* d_out, int out_size, void* d_ws, size_t ws_size,
                              hipStream_t stream)
{
    const float* x      = (const float*)d_in[0];
    const float* w_qkv  = (const float*)d_in[1];
    const float* b_qkv  = (const float*)d_in[2];
    const float* w_proj = (const float*)d_in[3];
    const float* b_proj = (const float*)d_in[4];
    const float* pe     = (const float*)d_in[5];
    float* outp = (float*)d_out;

    const size_t NEED = (size_t)2 * PERB * sizeof(bfr);  // 48 MiB
    if (ws_size < NEED) {
        fill_code<<<2048, 256, 0, stream>>>(outp, (float)(ws_size >> 20));
        return;
    }

    bfr* qT = (bfr*)d_ws;          // ws[0 .. PERB)      (aT aliases this)
    bfr* vT = qT + PERB;           // ws[PERB .. 2*PERB)

    for (int b = 0; b < NB; ++b) {
        bfr* kT = (bfr*)(outp + (size_t)b * PERB);  // d_out batch half
        bfr* aT = qT;
        qkv_mfma<<<dim3(9, 256, 1), 256, 0, stream>>>(
            x, w_qkv, b_qkv, qT, kT, vT, b);
        attn3d<<<dim3(512, 12, 1), 256, 0, stream>>>(qT, kT, vT, pe, aT);
        proj_mfma<<<dim3(3, 256, 1), 256, 0, stream>>>(
            aT, w_proj, b_proj, outp + (size_t)b * PERB);
    }
}

// Round 5
// 615.204 us; speedup vs baseline: 1.1772x; 1.1376x over previous
//
#include <hip/hip_runtime.h>

// ---------------------------------------------------------------------------
// SpatialAttention3D: B=2, C=384, D=H=W=32, HEADS=12, HD=32, WS=5, PAD=2
// I/O dtype: float32. Intermediates q/k/v/a: bf16.
// R10 = R9 + qkv staging fix:
//   - New xpose kernel: x[c][s] f32 -> xT[s][c] bf16 once per batch. The
//     16-way-conflicted scalar transpose leaves qkv's hot loop (was 5.8e7
//     conflict cycles/dispatch, 12x9 redundant executions of the transpose).
//   - qkv_mfma x-staging: pure b128 copies from xT (proj-style), and x
//     re-reads are bf16 (half the bytes).
//   - Buffers: xT + kT live in the spare batch-half of d_out (exact 48 MB):
//     proj(b) overwrites that half only after attn(b) consumed kT (stream
//     order). No extra workspace needed.
// attn3d / proj_mfma unchanged from R9.
// ---------------------------------------------------------------------------

#define NB 2
#define NC 384
#define NHEADS 12
#define NHD 32
#define NS 32768               // 32*32*32
#define PERB 12582912          // NC*NS (one batch of out / qkv third)
#define SCALE_F 0.17677669529663687f
#define LOG2E_F 1.4426950408889634f
#define SL_F (0.17677669529663687f * 1.4426950408889634f)   // SCALE*log2e

typedef unsigned short bfr;    // raw bf16 bits
typedef float floatx4 __attribute__((ext_vector_type(4)));
typedef float f32x4 __attribute__((ext_vector_type(4)));
typedef short bf16x8 __attribute__((ext_vector_type(8)));   // 8 bf16 = 1 b128
typedef short short4v __attribute__((ext_vector_type(4)));  // 4 bf16 = 1 b64

union B8 { floatx4 v; bfr h[8]; };

__device__ __forceinline__ float b2f(bfr u) {
    union { unsigned int i; float f; } v;
    v.i = (unsigned int)u << 16;
    return v.f;
}
__device__ __forceinline__ bfr f2b(float f) {
    union { float f; unsigned int i; } v;
    v.f = f;
    unsigned int x = v.i;
    return (bfr)((x + 0x7fffu + ((x >> 16) & 1u)) >> 16);  // RNE
}
// packed f32x2 -> bf16x2 (RNE), single instruction
__device__ __forceinline__ unsigned cvt_pk2(float lo, float hi) {
    unsigned r;
    asm("v_cvt_pk_bf16_f32 %0, %1, %2" : "=v"(r) : "v"(lo), "v"(hi));
    return r;
}

// diagnostic: encode ws_size (MiB) into the output if ws is too small
__global__ void fill_code(float* out, float code) {
    for (size_t i = (size_t)blockIdx.x*256 + threadIdx.x; i < (size_t)NB*PERB;
         i += (size_t)gridDim.x*256) out[i] = code;
}

// ---------------------------------------------------------------------------
// Kernel 0: xpose — x[b][c][s] f32 -> xT[s][c] bf16. grid (128), 256 threads.
// One-time transpose through LDS; conflicts here are paid once (not 9x12x).
// ---------------------------------------------------------------------------
__global__ __launch_bounds__(256) void xpose(
    const float* __restrict__ x, bfr* __restrict__ xT, int b)
{
    __shared__ __attribute__((aligned(16))) bfr tl[256][40];   // 20 KB
    const int tid = threadIdx.x;
    const int s0  = blockIdx.x * 256;
    for (int c0 = 0; c0 < NC; c0 += 32) {
        if (c0) __syncthreads();
        // load 32 c x 256 s (f32, coalesced), scatter bf16 into tl[s][c]
        const int c  = tid >> 3;            // 0..31
        const int sb = (tid & 7) * 4;       // 0..28
        #pragma unroll
        for (int j = 0; j < 8; ++j) {
            const int s4 = sb + j*32;
            floatx4 v =
                *(const floatx4*)&x[((size_t)b*NC + c0 + c)*NS + s0 + s4];
            #pragma unroll
            for (int i = 0; i < 4; ++i) tl[s4 + i][c] = f2b(v[i]);
        }
        __syncthreads();
        // write 256 rows x 32 c: one 64B line per thread
        floatx4* dst = (floatx4*)&xT[(size_t)(s0 + tid)*NC + c0];
        #pragma unroll
        for (int q = 0; q < 4; ++q)
            dst[q] = *(const floatx4*)&tl[tid][q*8];
    }
}

// ---------------------------------------------------------------------------
// Kernel 1: QKV GEMM, MFMA. grid (9 o-tiles FAST, 256 s-tiles), 256 threads.
// x operand now pre-transposed bf16 (xT) -> pure b128 staging.
// ---------------------------------------------------------------------------
__global__ __launch_bounds__(256) void qkv_mfma(
    const bfr* __restrict__ xT, const float* __restrict__ w,
    const float* __restrict__ bias,
    bfr* __restrict__ qT, bfr* __restrict__ kT, bfr* __restrict__ vT)
{
    __shared__ __attribute__((aligned(16))) bfr wl[128*40];   // [o][c] pad40
    __shared__ __attribute__((aligned(16))) bfr xl[128*40];   // [s][c] pad40
    __shared__ float bsh[128];
    const int tid  = threadIdx.x;
    const int lane = tid & 63;
    const int wave = tid >> 6;
    const int wo   = (wave & 1) * 64;     // wave o-quadrant
    const int wsq  = (wave >> 1) * 64;    // wave s-quadrant
    const int s0   = blockIdx.y * 128;
    const int o0   = blockIdx.x * 128;    // fast dim: 9 o-tiles share s-tile
    const int m16  = lane & 15;           // fragment row/col index
    const int g    = lane >> 4;           // k-chunk quarter (0..3)

    if (tid < 128) bsh[tid] = bias[o0 + tid];

    f32x4 acc[4][4];
    #pragma unroll
    for (int i = 0; i < 4; ++i)
        #pragma unroll
        for (int j = 0; j < 4; ++j) acc[i][j] = (f32x4){0.f, 0.f, 0.f, 0.f};

    for (int kc = 0; kc < 12; ++kc) {
        const int c0 = kc * 32;
        // stage w tile [128 o][32 c] f32->bf16 (1024 float4, 4 per thread)
        #pragma unroll
        for (int r = 0; r < 4; ++r) {
            const int idx = r*256 + tid;
            const int o   = idx >> 3;
            const int c4  = (idx & 7) * 4;
            floatx4 wv = *(const floatx4*)&w[(size_t)(o0 + o)*NC + c0 + c4];
            *(uint2*)&wl[o*40 + c4] =
                make_uint2(cvt_pk2(wv[0], wv[1]), cvt_pk2(wv[2], wv[3]));
        }
        // stage x tile [128 s][32 c] bf16: direct b128 copies (512, 2/thread)
        #pragma unroll
        for (int r = 0; r < 2; ++r) {
            const int idx = r*256 + tid;
            const int s   = idx >> 2;
            const int gg  = idx & 3;
            *(floatx4*)&xl[s*40 + gg*8] =
                *(const floatx4*)&xT[(size_t)(s0 + s)*NC + c0 + gg*8];
        }
        __syncthreads();
        bf16x8 af[4], bfg[4];
        #pragma unroll
        for (int i = 0; i < 4; ++i)
            af[i] = *(bf16x8*)&wl[(wo + i*16 + m16)*40 + g*8];
        #pragma unroll
        for (int j = 0; j < 4; ++j)
            bfg[j] = *(bf16x8*)&xl[(wsq + j*16 + m16)*40 + g*8];
        #pragma unroll
        for (int i = 0; i < 4; ++i)
            #pragma unroll
            for (int j = 0; j < 4; ++j)
                acc[i][j] = __builtin_amdgcn_mfma_f32_16x16x32_bf16(
                    af[i], bfg[j], acc[i][j], 0, 0, 0);
        __syncthreads();
    }

    // epilogue: +bias, bf16, heads layout. tensor uniform per block.
    const int tens = blockIdx.x / 3;            // 0=q,1=k,2=v
    bfr* dstT = (tens == 0) ? qT : ((tens == 1) ? kT : vT);
    const int remb = o0 - tens*NC;              // o offset within tensor
    const int q4   = g * 4;                     // C-layout row group
    #pragma unroll
    for (int i = 0; i < 4; ++i) {
        const int olb = wo + i*16 + q4;         // block-local o (mult of 4)
        const int ob  = remb + olb;
        const int hh  = ob >> 5;
        const int cc  = ob & 31;
        #pragma unroll
        for (int j = 0; j < 4; ++j) {
            const int s = s0 + wsq + j*16 + m16;
            const unsigned u0 = cvt_pk2(acc[i][j][0] + bsh[olb + 0],
                                        acc[i][j][1] + bsh[olb + 1]);
            const unsigned u1 = cvt_pk2(acc[i][j][2] + bsh[olb + 2],
                                        acc[i][j][3] + bsh[olb + 3]);
            *(uint2*)&dstT[((size_t)hh*NS + s)*NHD + cc] = make_uint2(u0, u1);
        }
    }
}

// ---------------------------------------------------------------------------
// Kernel 2: attn3d — unchanged from R9. grid (512, 12), 256 threads.
// ---------------------------------------------------------------------------
__global__ __launch_bounds__(256, 4) void attn3d(
    const bfr* __restrict__ qT, const bfr* __restrict__ kT,
    const bfr* __restrict__ vT, const float* __restrict__ pe,
    bfr* __restrict__ aT)
{
    // exact-fit 40960 B -> 4 blocks/CU
    __shared__ __attribute__((aligned(16))) unsigned char smem[40960];
    bfr (*kl)[40]   = reinterpret_cast<bfr(*)[40]>(smem);          // [128][40]
    bfr (*vtl)[136] = reinterpret_cast<bfr(*)[136]>(smem + 10240); // [32][136]
    bfr (*pel)[40]  = reinterpret_cast<bfr(*)[40]>(smem);          // overlay
    bfr (*ql)[40]   = reinterpret_cast<bfr(*)[40]>(smem + 18944);  // [64][40]
    bfr (*qpl)[132] = reinterpret_cast<bfr(*)[132]>(smem + 24064); // [64][132]

    const int tid  = threadIdx.x;
    const int lane = tid & 63;
    const int wave = tid >> 6;            // wave = qz within tile
    const int m16  = lane & 15;
    const int g    = lane >> 4;
    const int g4   = g << 2;
    const int bx   = blockIdx.x;
    const int tz = bx >> 6, ty = (bx >> 3) & 7, tx = bx & 7;
    const size_t hb = (size_t)blockIdx.y * NS;

    // ---- stage Q tile (one b128 per thread) ----
    {
        const int qr = tid >> 2, part = tid & 3;
        const int qzr = qr >> 4, qyr = (qr >> 2) & 3, qxr = qr & 3;
        const size_t sq =
            (size_t)(tz*4 + qzr)*1024 + (ty*4 + qyr)*32 + (tx*4 + qxr);
        *(floatx4*)&ql[qr][part*8] =
            *(const floatx4*)&qT[(hb + sq)*NHD + part*8];
    }
    // ---- stage pe transposed into overlay: pe[hd*125+n] -> pel[n][hd] ----
    for (int e = tid; e < 4000; e += 256) {
        const int hd = e / 125;
        const int n  = e - hd*125;
        pel[n][hd] = f2b(pe[e]);
    }
    if (tid < 96) pel[125 + (tid >> 5)][tid & 31] = 0;
    __syncthreads();

    const int wq = wave*16 + m16;                 // this lane's query row
    const bf16x8 bq = *(const bf16x8*)&ql[wq][g*8];

    // ---- QPE^T[n][q] = PE . Q^T, pre-scaled by SCALE*log2e -> qpl[q][n] ----
    #pragma unroll
    for (int t = 0; t < 8; ++t) {
        bf16x8 pa = *(const bf16x8*)&pel[t*16 + m16][g*8];
        f32x4 qa = __builtin_amdgcn_mfma_f32_16x16x32_bf16(
            pa, bq, (f32x4){0.f, 0.f, 0.f, 0.f}, 0, 0, 0);
        const unsigned w0 = cvt_pk2(qa[0]*SL_F, qa[1]*SL_F);
        const unsigned w1 = cvt_pk2(qa[2]*SL_F, qa[3]*SL_F);
        *(uint2*)&qpl[wq][t*16 + g4] = make_uint2(w0, w1);
    }
    if (g == 0) qpl[wq][128] = 0xFF80u;           // -inf sentinel column

    // ---- per-lane window table no[tt][r], packed 4x u8 per reg ----
    const int qy = m16 >> 2, qx = m16 & 3;
    unsigned nopk[4];
    #pragma unroll
    for (int tt = 0; tt < 4; ++tt) {
        unsigned v = 0;
        #pragma unroll
        for (int r = 0; r < 4; ++r) {
            const int t0 = g4 + r;
            const int hy = 2*tt + (t0 >> 3), hx = t0 & 7;
            const int dy = hy - qy, dx = hx - qx;
            const bool ok = ((unsigned)dy < 5u) && ((unsigned)dx < 5u);
            v |= (unsigned)(ok ? (dy*5 + dx) : 128) << (8*r);
        }
        nopk[tt] = v;
    }
    const bfr* qprow = qpl[wq];
    // bpermute byte-addrs for P redistribution
    const int a0 = (m16 + 32*(g & 1)) * 4;
    const int a1 = a0 + 64;
    const bool ghi = (g >= 2);

    float m = -1e30f, l = 0.f;
    f32x4 o[2];
    o[0] = (f32x4){0.f, 0.f, 0.f, 0.f};
    o[1] = (f32x4){0.f, 0.f, 0.f, 0.f};

    for (int c = 0; c < 4; ++c) {
        __syncthreads();   // prev-chunk reads (and pel/QPE reads for c=0) done
        // ---- stage K chunk: 128 keys x 32 c, zero-padded OOB ----
        #pragma unroll
        for (int r2 = 0; r2 < 2; ++r2) {
            const int idx = r2*256 + tid;
            const int key = idx >> 2, part = idx & 3;
            const int hz = key >> 6, hy = (key >> 3) & 7, hx = key & 7;
            const int gz = tz*4 - 2 + 2*c + hz, gy = ty*4 - 2 + hy,
                      gx = tx*4 - 2 + hx;
            floatx4 kv = (floatx4){0.f, 0.f, 0.f, 0.f};
            if ((unsigned)gz < 32u && (unsigned)gy < 32u && (unsigned)gx < 32u)
                kv = *(const floatx4*)
                     &kT[(hb + gz*1024 + gy*32 + gx)*NHD + part*8];
            *(floatx4*)&kl[key][part*8] = kv;
        }
        // ---- stage V^T chunk: key-pair packed b32 writes (conflict-free) ----
        {
            const int kp = tid & 63, hdo = tid >> 6;
            const int aK = 2*kp;                 // even key; pair never
            const int hz = aK >> 6;              // straddles a halo row
            const int hy = (aK >> 3) & 7, hx = aK & 7;
            const int gz = tz*4 - 2 + 2*c + hz, gy = ty*4 - 2 + hy,
                      gx = tx*4 - 2 + hx;
            const bool vzy = ((unsigned)gz < 32u) && ((unsigned)gy < 32u);
            B8 va, vb;
            va.v = (floatx4){0.f, 0.f, 0.f, 0.f};
            vb.v = (floatx4){0.f, 0.f, 0.f, 0.f};
            const size_t gb = hb + gz*1024 + gy*32;
            if (vzy && (unsigned)gx < 32u)
                va.v = *(const floatx4*)&vT[(gb + gx)*NHD + hdo*8];
            if (vzy && (unsigned)(gx + 1) < 32u)
                vb.v = *(const floatx4*)&vT[(gb + gx + 1)*NHD + hdo*8];
            #pragma unroll
            for (int i = 0; i < 8; ++i) {
                const unsigned u = (unsigned)va.h[i] | ((unsigned)vb.h[i] << 16);
                *(unsigned*)&vtl[hdo*8 + i][aK] = u;
            }
        }
        __syncthreads();   // chunk staged

        #pragma unroll
        for (int zl = 0; zl < 2; ++zl) {
            const int dz = 2*c + zl - wave;       // wave-uniform
            if ((unsigned)dz > 4u) continue;      // skip invalid z layer
            const int nz = dz * 25;
            // ---- S^T tile = K . Q^T (4 MFMAs, 64 keys) ----
            f32x4 s[4];
            __builtin_amdgcn_s_setprio(1);
            #pragma unroll
            for (int tt = 0; tt < 4; ++tt) {
                bf16x8 ka = *(const bf16x8*)&kl[zl*64 + tt*16 + m16][g*8];
                s[tt] = __builtin_amdgcn_mfma_f32_16x16x32_bf16(
                    ka, bq, (f32x4){0.f, 0.f, 0.f, 0.f}, 0, 0, 0);
            }
            __builtin_amdgcn_s_setprio(0);
            // ---- biased+masked scores (log2 domain), layer max ----
            float mx = -1e30f;
            #pragma unroll
            for (int tt = 0; tt < 4; ++tt) {
                #pragma unroll
                for (int r = 0; r < 4; ++r) {
                    const unsigned n =
                        min((unsigned)nz + ((nopk[tt] >> (8*r)) & 255u), 128u);
                    const float qb  = b2f(qprow[n]);   // -inf when masked
                    const float val = fmaf(s[tt][r], SL_F, qb);
                    s[tt][r] = val;
                    mx = fmaxf(mx, val);
                }
            }
            mx = fmaxf(mx, __shfl_xor(mx, 16));
            mx = fmaxf(mx, __shfl_xor(mx, 32));
            const float mn = fmaxf(m, mx);
            // ---- T13: rescale only if some lane's max grew (al==1 else) ----
            if (__any(mx > m)) {
                const float al = exp2f(m - mn);
                l *= al;
                #pragma unroll
                for (int i = 0; i < 4; ++i) { o[0][i] *= al; o[1][i] *= al; }
                m = mn;
            }
            // ---- P = exp2(S - m), bf16-packed via cvt_pk ----
            float ls = 0.f;
            unsigned pk[4][2];
            #pragma unroll
            for (int tt = 0; tt < 4; ++tt) {
                const float p0 = exp2f(s[tt][0] - m);
                const float p1 = exp2f(s[tt][1] - m);
                const float p2 = exp2f(s[tt][2] - m);
                const float p3 = exp2f(s[tt][3] - m);
                ls += (p0 + p1) + (p2 + p3);
                pk[tt][0] = cvt_pk2(p0, p1);
                pk[tt][1] = cvt_pk2(p2, p3);
            }
            ls += __shfl_xor(ls, 16);
            ls += __shfl_xor(ls, 32);
            l += ls;
            // ---- O^T += V^T . P^T; P B-frag via bpermute ----
            // lane (m16,g) needs P[q=m16][k=ksl*32+g*8+j]; src lane
            // m16+16*(2*(g&1)+(w>>1)), tile tt=2*ksl+(g>>1), word (w&1).
            #pragma unroll
            for (int ksl = 0; ksl < 2; ++ksl) {
                union { unsigned u[4]; bf16x8 v; } pb;
                #pragma unroll
                for (int w = 0; w < 4; ++w) {
                    const int ad = (w < 2) ? a0 : a1;
                    const int wi = w & 1;
                    const int lo = __builtin_amdgcn_ds_bpermute(
                        ad, (int)pk[2*ksl][wi]);
                    const int hi = __builtin_amdgcn_ds_bpermute(
                        ad, (int)pk[2*ksl + 1][wi]);
                    pb.u[w] = ghi ? (unsigned)hi : (unsigned)lo;
                }
                __builtin_amdgcn_s_setprio(1);
                #pragma unroll
                for (int mt = 0; mt < 2; ++mt) {
                    bf16x8 va = *(const bf16x8*)
                        &vtl[mt*16 + m16][zl*64 + ksl*32 + g*8];
                    o[mt] = __builtin_amdgcn_mfma_f32_16x16x32_bf16(
                        va, pb.v, o[mt], 0, 0, 0);
                }
                __builtin_amdgcn_s_setprio(0);
            }
        }
    }

    // ---- normalize + store: lane holds O^T[hd = mt*16+g4+r][q = wq] ----
    const float rl = 1.f / l;
    const size_t sq = (size_t)(tz*4 + wave)*1024 + (ty*4 + qy)*32 + (tx*4 + qx);
    #pragma unroll
    for (int mt = 0; mt < 2; ++mt) {
        const unsigned w0 = cvt_pk2(o[mt][0]*rl, o[mt][1]*rl);
        const unsigned w1 = cvt_pk2(o[mt][2]*rl, o[mt][3]*rl);
        *(uint2*)&aT[(hb + sq)*NHD + mt*16 + g4] = make_uint2(w0, w1);
    }
}

// ---------------------------------------------------------------------------
// Kernel 3: proj GEMM, MFMA. grid (3 o-tiles FAST, 256 s-tiles), 256 threads.
// ---------------------------------------------------------------------------
__global__ __launch_bounds__(256) void proj_mfma(
    const bfr* __restrict__ aT, const float* __restrict__ w,
    const float* __restrict__ bias, float* __restrict__ out)
{
    __shared__ __attribute__((aligned(16))) bfr wl[128*40];   // [o][c] pad40
    __shared__ __attribute__((aligned(16))) bfr xl[128*40];   // [s][c] pad40
    __shared__ float bsh[128];
    const int tid  = threadIdx.x;
    const int lane = tid & 63;
    const int wave = tid >> 6;
    const int wo   = (wave & 1) * 64;
    const int wsq  = (wave >> 1) * 64;
    const int s0   = blockIdx.y * 128;
    const int o0   = blockIdx.x * 128;    // fast dim
    const int m16  = lane & 15;
    const int g    = lane >> 4;

    if (tid < 128) bsh[tid] = bias[o0 + tid];

    f32x4 acc[4][4];
    #pragma unroll
    for (int i = 0; i < 4; ++i)
        #pragma unroll
        for (int j = 0; j < 4; ++j) acc[i][j] = (f32x4){0.f, 0.f, 0.f, 0.f};

    for (int kc = 0; kc < 12; ++kc) {          // kc == head
        const int c0 = kc * 32;
        // stage w tile [128 o][32 c] f32->bf16
        #pragma unroll
        for (int r = 0; r < 4; ++r) {
            const int idx = r*256 + tid;
            const int o   = idx >> 3;
            const int c4  = (idx & 7) * 4;
            floatx4 wv = *(const floatx4*)&w[(size_t)(o0 + o)*NC + c0 + c4];
            *(uint2*)&wl[o*40 + c4] =
                make_uint2(cvt_pk2(wv[0], wv[1]), cvt_pk2(wv[2], wv[3]));
        }
        // stage a tile: [128 s][32 c] bf16, direct b128 copies (512, 2/thread)
        #pragma unroll
        for (int r = 0; r < 2; ++r) {
            const int idx = r*256 + tid;
            const int s   = idx >> 2;
            const int gg  = idx & 3;
            *(floatx4*)&xl[s*40 + gg*8] =
                *(const floatx4*)&aT[((size_t)kc*NS + s0 + s)*NHD + gg*8];
        }
        __syncthreads();
        bf16x8 af[4], bfg[4];
        #pragma unroll
        for (int i = 0; i < 4; ++i)
            af[i] = *(bf16x8*)&wl[(wo + i*16 + m16)*40 + g*8];
        #pragma unroll
        for (int j = 0; j < 4; ++j)
            bfg[j] = *(bf16x8*)&xl[(wsq + j*16 + m16)*40 + g*8];
        #pragma unroll
        for (int i = 0; i < 4; ++i)
            #pragma unroll
            for (int j = 0; j < 4; ++j)
                acc[i][j] = __builtin_amdgcn_mfma_f32_16x16x32_bf16(
                    af[i], bfg[j], acc[i][j], 0, 0, 0);
        __syncthreads();
    }

    // epilogue: +bias, f32 channel-major out[o][s]
    const int q4 = g * 4;
    #pragma unroll
    for (int i = 0; i < 4; ++i) {
        const int olb = wo + i*16 + q4;
        #pragma unroll
        for (int j = 0; j < 4; ++j) {
            const int s = s0 + wsq + j*16 + m16;
            #pragma unroll
            for (int r = 0; r < 4; ++r)
                out[(size_t)(o0 + olb + r)*NS + s] = acc[i][j][r] + bsh[olb + r];
        }
    }
}

// ---------------------------------------------------------------------------
extern "C" void kernel_launch(void* const* d_in, const int* in_sizes, int n_in,
                              void* d_out, int out_size, void* d_ws, size_t ws_size,
                              hipStream_t stream)
{
    const float* x      = (const float*)d_in[0];
    const float* w_qkv  = (const float*)d_in[1];
    const float* b_qkv  = (const float*)d_in[2];
    const float* w_proj = (const float*)d_in[3];
    const float* b_proj = (const float*)d_in[4];
    const float* pe     = (const float*)d_in[5];
    float* outp = (float*)d_out;

    const size_t NEED = (size_t)2 * PERB * sizeof(bfr);  // 48 MiB
    if (ws_size < NEED) {
        fill_code<<<2048, 256, 0, stream>>>(outp, (float)(ws_size >> 20));
        return;
    }

    bfr* qT = (bfr*)d_ws;          // ws[0 .. PERB)      (aT aliases this)
    bfr* vT = qT + PERB;           // ws[PERB .. 2*PERB)
    // scratch in d_out's second batch-half (48 MB = 24 MB xT + 24 MB kT);
    // proj(b) overwrites it only after attn(b) consumed kT (stream order).
    bfr* xT = (bfr*)(outp + PERB);
    bfr* kT = xT + (size_t)PERB;

    for (int b = 0; b < NB; ++b) {
        bfr* aT = qT;
        xpose<<<dim3(128, 1, 1), 256, 0, stream>>>(x, xT, b);
        qkv_mfma<<<dim3(9, 256, 1), 256, 0, stream>>>(
            xT, w_qkv, b_qkv, qT, kT, vT);
        attn3d<<<dim3(512, 12, 1), 256, 0, stream>>>(qT, kT, vT, pe, aT);
        proj_mfma<<<dim3(3, 256, 1), 256, 0, stream>>>(
            aT, w_proj, b_proj, outp + (size_t)b * PERB);
    }
}